// Round 3
// baseline (735.419 us; speedup 1.0000x reference)
//
#include <hip/hip_runtime.h>
#include <hip/hip_bf16.h>
#include <stdint.h>

#define T_TOKENS 4096   // B*S
#define H_DIM    1024
#define F_DIM    4096
#define NE       8
#define NA       8192   // 2*T (total expert assignments)

typedef __bf16 bf16x8 __attribute__((ext_vector_type(8)));
typedef float  f32x4  __attribute__((ext_vector_type(4)));

__device__ __forceinline__ float b2f(unsigned short u) {
    union { float f; uint32_t i; } v; v.i = ((uint32_t)u) << 16; return v.f;
}
__device__ __forceinline__ unsigned short f2b(float f) {
    union { float f; uint32_t i; } v; v.f = f;
    uint32_t x = v.i;
    return (unsigned short)((x + 0x7FFFu + ((x >> 16) & 1u)) >> 16);
}

// exact GELU via A&S 7.1.26 erf (max err 1.5e-7), branchless, ~14 VALU + v_exp
__device__ __forceinline__ float gelu_f(float x) {
    float z = fabsf(x) * 0.70710678118f;
    float t = 1.0f / (1.0f + 0.3275911f * z);
    float p = t * (0.254829592f + t * (-0.284496736f +
              t * (1.421413741f + t * (-1.453152027f + t * 1.061405429f))));
    float erf_z = 1.0f - p * __expf(-z * z);
    float sgn_erf = (x >= 0.f) ? erf_z : -erf_z;
    return x * (0.5f + 0.5f * sgn_erf);
}

// async global->LDS, 16B per lane; LDS dest = wave-uniform base + lane*16.
__device__ __forceinline__ void gl_lds16(const void* g, void* l) {
    __builtin_amdgcn_global_load_lds(
        (const __attribute__((address_space(1))) void*)g,
        (__attribute__((address_space(3))) void*)l,
        16, 0, 0);
}

// ---- dtype probe: flag=1 if inputs are fp32, 0 if bf16 --------------------
__global__ void probe_kernel(const unsigned short* __restrict__ hs,
                             int* __restrict__ flag) {
    int lane = threadIdx.x;  // 64 threads
    int cnt = 0;
    for (int j = 0; j < 16; j++) {
        unsigned short u = hs[(lane * 16 + j) * 2];  // even indices only
        int e = (u >> 7) & 0xFF;
        if (e >= 100 && e <= 135) cnt++;
    }
    for (int off = 32; off > 0; off >>= 1) cnt += __shfl_down(cnt, off);
    if (lane == 0) *flag = (cnt >= 512) ? 0 : 1;  // bf16: ~1024, fp32: ~140
}

// ---- router (one wave per token) + fused hs->bf16 conversion --------------
__global__ __launch_bounds__(256) void router_kernel(
    const void* __restrict__ hs, const void* __restrict__ rw,
    const void* __restrict__ rb, const int* __restrict__ flag,
    int* __restrict__ top_i, float* __restrict__ top_w,
    unsigned short* __restrict__ hsb) {
    bool f32 = (*flag != 0);
    int wave = threadIdx.x >> 6, lane = threadIdx.x & 63;
    int t = blockIdx.x * 4 + wave;
    unsigned short* hout = hsb + (size_t)t * H_DIM;
    float acc[NE];
#pragma unroll
    for (int e = 0; e < NE; e++) acc[e] = 0.f;
    if (f32) {
        const float* hrow = (const float*)hs + (size_t)t * H_DIM;
        const float* rwf = (const float*)rw;
        for (int j = 0; j < 16; j++) {
            int k = j * 64 + lane;
            float h = hrow[k];
            hout[k] = f2b(h);
            float4 a = *(const float4*)(rwf + (size_t)k * NE);
            float4 b = *(const float4*)(rwf + (size_t)k * NE + 4);
            acc[0] += h * a.x; acc[1] += h * a.y; acc[2] += h * a.z; acc[3] += h * a.w;
            acc[4] += h * b.x; acc[5] += h * b.y; acc[6] += h * b.z; acc[7] += h * b.w;
        }
    } else {
        const unsigned short* hrow = (const unsigned short*)hs + (size_t)t * H_DIM;
        const unsigned short* rwu = (const unsigned short*)rw;
        for (int j = 0; j < 16; j++) {
            int k = j * 64 + lane;
            unsigned short hu = hrow[k];
            hout[k] = hu;
            float h = b2f(hu);
            uint4 rv = *(const uint4*)(rwu + (size_t)k * NE);
            const unsigned short* rs = (const unsigned short*)&rv;
#pragma unroll
            for (int e = 0; e < NE; e++) acc[e] += h * b2f(rs[e]);
        }
    }
#pragma unroll
    for (int e = 0; e < NE; e++)
        for (int off = 32; off > 0; off >>= 1) acc[e] += __shfl_down(acc[e], off);
    if (lane == 0) {
        float lg[NE];
#pragma unroll
        for (int e = 0; e < NE; e++)
            lg[e] = acc[e] + (f32 ? ((const float*)rb)[e]
                                  : b2f(((const unsigned short*)rb)[e]));
        int e0 = 0;
        for (int e = 1; e < NE; e++) if (lg[e] > lg[e0]) e0 = e;
        int e1 = (e0 == 0) ? 1 : 0;
        for (int e = 0; e < NE; e++) if (e != e0 && lg[e] > lg[e1]) e1 = e;
        float w0 = 1.f / (1.f + expf(lg[e1] - lg[e0]));
        top_i[t * 2] = e0; top_i[t * 2 + 1] = e1;
        top_w[t * 2] = w0; top_w[t * 2 + 1] = 1.f - w0;
    }
}

// ---- assignment build: one block; also zeroes the transpose work counter --
__global__ __launch_bounds__(256) void assign_kernel(
    const int* __restrict__ top_i, const float* __restrict__ top_w,
    int* __restrict__ token_list, float* __restrict__ wgt_list,
    int* __restrict__ assign_row, int* __restrict__ counts,
    int* __restrict__ offsets, int* __restrict__ ctr) {
    __shared__ int cnt_s[NE], cur_s[NE];
    int tid = threadIdx.x;
    if (tid < NE) cnt_s[tid] = 0;
    if (tid == 0) *ctr = 0;
    __syncthreads();
    for (int idx = tid; idx < NA; idx += 256) atomicAdd(&cnt_s[top_i[idx]], 1);
    __syncthreads();
    if (tid == 0) {
        int run = 0;
        for (int e = 0; e < NE; e++) {
            offsets[e] = run; counts[e] = cnt_s[e]; cur_s[e] = run; run += cnt_s[e];
        }
    }
    __syncthreads();
    for (int idx = tid; idx < NA; idx += 256) {
        int e = top_i[idx];
        int pos = atomicAdd(&cur_s[e], 1);
        token_list[pos] = idx >> 1;
        wgt_list[pos] = top_w[idx];
        assign_row[idx] = pos;
    }
}

// ---- 64x64 transpose to bf16 (from fp32 or bf16), per expert slice z ------
__global__ __launch_bounds__(256) void transpose_kernel(
    const void* __restrict__ in, unsigned short* __restrict__ out,
    int R, int C, const int* __restrict__ flag) {
    bool f32 = (*flag != 0);
    size_t zo = (size_t)blockIdx.z * R * C;
    int c0 = blockIdx.x * 64, r0 = blockIdx.y * 64;
    __shared__ unsigned short t[64][65];
    int tx = threadIdx.x & 15, ty = threadIdx.x >> 4;  // 16 col-groups x 16 rows
    if (f32) {
        const float* inf = (const float*)in + zo;
#pragma unroll
        for (int i = 0; i < 4; i++) {
            int r = ty + i * 16;
            float4 v = *(const float4*)&inf[(size_t)(r0 + r) * C + c0 + tx * 4];
            t[r][tx * 4] = f2b(v.x); t[r][tx * 4 + 1] = f2b(v.y);
            t[r][tx * 4 + 2] = f2b(v.z); t[r][tx * 4 + 3] = f2b(v.w);
        }
    } else {
        const unsigned short* inu = (const unsigned short*)in + zo;
#pragma unroll
        for (int i = 0; i < 4; i++) {
            int r = ty + i * 16;
            ushort4 v = *(const ushort4*)&inu[(size_t)(r0 + r) * C + c0 + tx * 4];
            t[r][tx * 4] = v.x; t[r][tx * 4 + 1] = v.y;
            t[r][tx * 4 + 2] = v.z; t[r][tx * 4 + 3] = v.w;
        }
    }
    __syncthreads();
#pragma unroll
    for (int i = 0; i < 4; i++) {
        int cc = ty + i * 16;
        ushort4 w;
        w.x = t[tx * 4][cc]; w.y = t[tx * 4 + 1][cc];
        w.z = t[tx * 4 + 2][cc]; w.w = t[tx * 4 + 3][cc];
        *(ushort4*)&out[zo + (size_t)(c0 + cc) * R + r0 + tx * 4] = w;
    }
}

// ---- grouped GEMM + fused work-stealing w2 transpose ----------------------
// MODE 0: 256 thr (4 waves 2x2), BM=128 BN=128, acc[4][4]
//         act = gelu(hsb[gathered] @ w1t^T + b1)  -> bf16
//         idle blocks + grid.z==8 slice steal 64x64 w2-transpose tiles.
// MODE 1: 512 thr (8 waves 4x2), BM=256 BN=128, acc[4][4]
//         y   = (act @ w2t^T + b2) * slot_wgt     -> bf16
// XCD swizzle: expert = lid % 8 (one expert per XCD); n fastest within expert.
// LDS row = 32 k-elems (64B = 4 chunks of 16B); row r chunk q at slot q^(r&3).
template <int MODE>
__global__ __launch_bounds__((MODE == 0) ? 256 : 512) void gemm_kernel(
    const unsigned short* __restrict__ Abase,
    const unsigned short* __restrict__ Bt,   // [E][N][K] bf16 transposed weights
    const void* __restrict__ bias,           // [E][N] fp32 or bf16 per flag
    const int* __restrict__ flag,
    const int* __restrict__ token_list, const float* __restrict__ wgt_list,
    const int* __restrict__ counts, const int* __restrict__ offsets,
    unsigned short* __restrict__ act_out, unsigned short* __restrict__ y_out,
    const void* __restrict__ tsrc,           // w2 source for fused transpose
    unsigned short* __restrict__ tdst,       // wt2 dest
    int* __restrict__ ctr, int ntiles) {
    constexpr int K     = (MODE == 0) ? H_DIM : F_DIM;
    constexpr int NDIM  = (MODE == 0) ? F_DIM : H_DIM;
    constexpr int AST   = K;
    constexpr int BM    = (MODE == 0) ? 128 : 256;
    constexpr int BN    = 128;
    constexpr int WAVES = (MODE == 0) ? 4 : 8;
    constexpr int WM    = (MODE == 0) ? 2 : 4;
    constexpr int WN    = 2;
    constexpr int MI    = BM / (16 * WM);   // 4
    constexpr int NJ    = BN / (16 * WN);   // 4
    constexpr int NK    = K / 32;
    constexpr int ABUF  = BM * 32;
    constexpr int BBUF  = BN * 32;
    constexpr int NIA   = BM / (16 * WAVES);  // 2
    constexpr int NIB   = BN / (16 * WAVES);  // 2 or 1

    __shared__ __bf16 As[2 * ABUF];
    __shared__ __bf16 Bs[2 * BBUF];
    __shared__ int   tok_s[BM];
    __shared__ float wgt_s[BM];
    __shared__ int   c_s;

    const int tid = threadIdx.x;
    const bool f32 = (*flag != 0);

    // ---- bijective XCD-aware remap; role split ----
    const int lid = blockIdx.x + gridDim.x * (blockIdx.y + gridDim.y * blockIdx.z);
    const int NG = gridDim.x * gridDim.y * NE;
    bool gemm_role = (lid < NG);
    int e = 0, m0 = 0, cnt = 0, n0 = 0, off = 0;
    if (gemm_role) {
        e = lid & 7;
        int r_ = lid >> 3;
        int nx = r_ % gridDim.x;           // n fastest: A panel reuse in L2
        int my = r_ / gridDim.x;
        cnt = counts[e];
        m0 = my * BM;
        off = offsets[e];
        n0 = nx * BN;
        gemm_role = (m0 < cnt);
    }

    if (gemm_role) {
        const int wave = tid >> 6, lane = tid & 63;

        if (tid < BM) {
            int r = off + min(m0 + tid, cnt - 1);
            tok_s[tid] = (MODE == 0) ? token_list[r] : r;
            wgt_s[tid] = wgt_list[r];
        }
        __syncthreads();

        // staging addresses (1KB per instr = 16 rows x 64B)
        const char* Abytes = (const char*)Abase;
        const char* Bbytes = (const char*)(Bt + (size_t)e * NDIM * K);
        const int rl = lane >> 2;                       // row within instr (0..15)
        const int chk = (lane & 3) ^ (rl & 3);          // global chunk fetched
        uint64_t ga[NIA], gb[NIB];
        uint32_t la[NIA], lb[NIB];
#pragma unroll
        for (int j = 0; j < NIA; j++) {
            int rowA = (wave * NIA + j) * 16 + rl;
            ga[j] = (uint64_t)(uintptr_t)(Abytes + ((size_t)tok_s[rowA] * AST + chk * 8) * 2);
            la[j] = (wave * NIA + j) * 512;             // element offset
        }
#pragma unroll
        for (int j = 0; j < NIB; j++) {
            int rowB = n0 + (wave * NIB + j) * 16 + rl;
            gb[j] = (uint64_t)(uintptr_t)(Bbytes + ((size_t)rowB * K + chk * 8) * 2);
            lb[j] = (wave * NIB + j) * 512;
        }

        f32x4 acc[MI][NJ];
#pragma unroll
        for (int i = 0; i < MI; i++)
#pragma unroll
            for (int j = 0; j < NJ; j++) acc[i][j] = (f32x4){0.f, 0.f, 0.f, 0.f};

        const int wr = wave / WN, wc = wave % WN;
        const int lane15 = lane & 15, quad = lane >> 4;

        // prologue: stage tile 0 into buffer 0
#pragma unroll
        for (int j = 0; j < NIA; j++) {
            gl_lds16((const void*)(uintptr_t)ga[j], (void*)(As + la[j]));
            ga[j] += 64;
        }
#pragma unroll
        for (int j = 0; j < NIB; j++) {
            gl_lds16((const void*)(uintptr_t)gb[j], (void*)(Bs + lb[j]));
            gb[j] += 64;
        }
        __syncthreads();

        for (int kt = 0; kt < NK; kt++) {
            const int cur = kt & 1;
            if (kt + 1 < NK) {  // stage next tile into alt buffer (async)
                const int nxt = cur ^ 1;
#pragma unroll
                for (int j = 0; j < NIA; j++) {
                    gl_lds16((const void*)(uintptr_t)ga[j], (void*)(As + nxt * ABUF + la[j]));
                    ga[j] += 64;
                }
#pragma unroll
                for (int j = 0; j < NIB; j++) {
                    gl_lds16((const void*)(uintptr_t)gb[j], (void*)(Bs + nxt * BBUF + lb[j]));
                    gb[j] += 64;
                }
            }
            const __bf16* Ab = As + cur * ABUF;
            const __bf16* Bb = Bs + cur * BBUF;
            bf16x8 a[MI], b[NJ];
#pragma unroll
            for (int i = 0; i < MI; i++) {
                int row = wr * (BM / WM) + i * 16 + lane15;
                a[i] = *(const bf16x8*)&Ab[row * 32 + ((quad ^ (row & 3)) * 8)];
            }
#pragma unroll
            for (int j = 0; j < NJ; j++) {
                int row = wc * (BN / WN) + j * 16 + lane15;
                b[j] = *(const bf16x8*)&Bb[row * 32 + ((quad ^ (row & 3)) * 8)];
            }
#pragma unroll
            for (int i = 0; i < MI; i++)
#pragma unroll
                for (int j = 0; j < NJ; j++)
                    acc[i][j] = __builtin_amdgcn_mfma_f32_16x16x32_bf16(a[i], b[j], acc[i][j], 0, 0, 0);
            __syncthreads();  // drains next tile's async loads + frees cur buffer
        }

        // epilogue: C/D layout col=lane&15, row=quad*4+reg
#pragma unroll
        for (int j = 0; j < NJ; j++) {
            int col = n0 + wc * (BN / WN) + j * 16 + lane15;
            float bv = f32 ? ((const float*)bias)[(size_t)e * NDIM + col]
                           : b2f(((const unsigned short*)bias)[(size_t)e * NDIM + col]);
#pragma unroll
            for (int i = 0; i < MI; i++) {
#pragma unroll
                for (int r = 0; r < 4; r++) {
                    int rowl = wr * (BM / WM) + i * 16 + quad * 4 + r;
                    if (m0 + rowl < cnt) {
                        float v = acc[i][j][r] + bv;
                        if (MODE == 0) {
                            act_out[(size_t)(off + m0 + rowl) * F_DIM + col] = f2b(gelu_f(v));
                        } else {
                            y_out[(size_t)(off + m0 + rowl) * H_DIM + col] = f2b(v * wgt_s[rowl]);
                        }
                    }
                }
            }
        }
        return;
    }

    // ---- transpose work-stealing (idle gemm blocks + dedicated z slice) ----
    // w2 [E][F][H] fp32/bf16 -> tdst [E][H][F] bf16, 64x64 tiles, 256 threads.
    if (ntiles <= 0) return;
    unsigned short (*tt)[65] = (unsigned short(*)[65])As;  // 8320B alias, fits
    const int tx = tid & 15, ty = (tid >> 4) & 15;
    for (;;) {
        if (tid == 0) c_s = atomicAdd(ctr, 1);
        __syncthreads();
        int c = c_s;
        if (c >= ntiles) break;
        int e2 = c >> 10;                 // 1024 tiles per expert slice
        int rem = c & 1023;
        int c0 = (rem & 15) * 64;         // H-col tile (16 of them)
        int r0 = (rem >> 4) * 64;         // F-row tile (64 of them)
        size_t zo = (size_t)e2 * F_DIM * H_DIM;
        if (f32) {
            const float* inf = (const float*)tsrc + zo;
#pragma unroll
            for (int i = 0; i < 4; i++) {
                int r = ty + i * 16;
                float4 v = *(const float4*)&inf[(size_t)(r0 + r) * H_DIM + c0 + tx * 4];
                tt[r][tx * 4] = f2b(v.x); tt[r][tx * 4 + 1] = f2b(v.y);
                tt[r][tx * 4 + 2] = f2b(v.z); tt[r][tx * 4 + 3] = f2b(v.w);
            }
        } else {
            const unsigned short* inu = (const unsigned short*)tsrc + zo;
#pragma unroll
            for (int i = 0; i < 4; i++) {
                int r = ty + i * 16;
                ushort4 v = *(const ushort4*)&inu[(size_t)(r0 + r) * H_DIM + c0 + tx * 4];
                tt[r][tx * 4] = v.x; tt[r][tx * 4 + 1] = v.y;
                tt[r][tx * 4 + 2] = v.z; tt[r][tx * 4 + 3] = v.w;
            }
        }
        __syncthreads();
#pragma unroll
        for (int i = 0; i < 4; i++) {
            int cc = ty + i * 16;
            ushort4 w;
            w.x = tt[tx * 4][cc]; w.y = tt[tx * 4 + 1][cc];
            w.z = tt[tx * 4 + 2][cc]; w.w = tt[tx * 4 + 3][cc];
            *(ushort4*)&tdst[zo + (size_t)(c0 + cc) * F_DIM + r0 + tx * 4] = w;
        }
        __syncthreads();
    }
}

// ---- combine: out[t] = y[slot0] + y[slot1]; write bf16 or fp32 ------------
__global__ __launch_bounds__(256) void combine_kernel(
    const unsigned short* __restrict__ y, const int* __restrict__ assign_row,
    void* __restrict__ out, const int* __restrict__ flag) {
    bool f32 = (*flag != 0);
    int t = blockIdx.x;
    int r0 = assign_row[t * 2], r1 = assign_row[t * 2 + 1];
    ushort4 a = ((const ushort4*)(y + (size_t)r0 * H_DIM))[threadIdx.x];
    ushort4 b = ((const ushort4*)(y + (size_t)r1 * H_DIM))[threadIdx.x];
    float s0 = b2f(a.x) + b2f(b.x), s1 = b2f(a.y) + b2f(b.y);
    float s2 = b2f(a.z) + b2f(b.z), s3 = b2f(a.w) + b2f(b.w);
    if (f32) {
        float4 o = {s0, s1, s2, s3};
        ((float4*)out)[(size_t)t * (H_DIM / 4) + threadIdx.x] = o;
    } else {
        ushort4 o;
        o.x = f2b(s0); o.y = f2b(s1); o.z = f2b(s2); o.w = f2b(s3);
        ((ushort4*)((unsigned short*)out + (size_t)t * H_DIM))[threadIdx.x] = o;
    }
}

extern "C" void kernel_launch(void* const* d_in, const int* in_sizes, int n_in,
                              void* d_out, int out_size, void* d_ws, size_t ws_size,
                              hipStream_t stream) {
    const void* hs = d_in[0];
    const void* rw = d_in[1];
    const void* rb = d_in[2];
    const void* w1 = d_in[3];
    const void* b1 = d_in[4];
    const void* w2 = d_in[5];
    const void* b2 = d_in[6];

    char* ws = (char*)d_ws;
    size_t o = 0;
    auto alloc = [&](size_t bytes) {
        char* p = ws + o; o += (bytes + 255) & ~(size_t)255; return p;
    };
    unsigned short* wt1  = (unsigned short*)alloc((size_t)NE * F_DIM * H_DIM * 2);  // 64 MB
    unsigned short* act  = (unsigned short*)alloc((size_t)NA * F_DIM * 2);          // 64 MB
    unsigned short* yb   = (unsigned short*)alloc((size_t)NA * H_DIM * 2);          // 16 MB
    unsigned short* hsb  = (unsigned short*)alloc((size_t)T_TOKENS * H_DIM * 2);    //  8 MB
    int*   top_i      = (int*)alloc(NA * 4);
    float* top_w      = (float*)alloc(NA * 4);
    int*   token_list = (int*)alloc(NA * 4);
    float* wgt_list   = (float*)alloc(NA * 4);
    int*   assign_row = (int*)alloc(NA * 4);
    int*   counts     = (int*)alloc(64);
    int*   offsets    = (int*)alloc(64);
    int*   flag       = (int*)alloc(64);
    int*   ctr        = (int*)alloc(64);
    unsigned short* wt2 = (unsigned short*)alloc((size_t)NE * F_DIM * H_DIM * 2);   // 64 MB (fused path)
    const bool fused = (o <= ws_size);
    if (!fused) wt2 = wt1;  // fall back: reuse wt1 with a separate transpose launch
    (void)in_sizes; (void)n_in; (void)out_size;

    probe_kernel<<<1, 64, 0, stream>>>((const unsigned short*)hs, flag);
    router_kernel<<<T_TOKENS / 4, 256, 0, stream>>>(hs, rw, rb, flag, top_i, top_w, hsb);
    assign_kernel<<<1, 256, 0, stream>>>(top_i, top_w, token_list, wgt_list,
                                         assign_row, counts, offsets, ctr);
    transpose_kernel<<<dim3(F_DIM / 64, H_DIM / 64, NE), 256, 0, stream>>>(
        w1, wt1, H_DIM, F_DIM, flag);
    if (fused) {
        // grid.z = 9: z slices 0..7 carry gemm blocks (e = lid%8 swizzle);
        // slice 8 + idle gemm blocks steal w2-transpose tiles into wt2.
        gemm_kernel<0><<<dim3(F_DIM / 128, T_TOKENS / 128, NE + 1), 256, 0, stream>>>(
            hsb, wt1, b1, flag, token_list, wgt_list, counts, offsets, act, nullptr,
            w2, wt2, ctr, (H_DIM / 64) * (F_DIM / 64) * NE);
    } else {
        gemm_kernel<0><<<dim3(F_DIM / 128, T_TOKENS / 128, NE), 256, 0, stream>>>(
            hsb, wt1, b1, flag, token_list, wgt_list, counts, offsets, act, nullptr,
            w2, wt2, ctr, 0);
        transpose_kernel<<<dim3(H_DIM / 64, F_DIM / 64, NE), 256, 0, stream>>>(
            w2, wt1, F_DIM, H_DIM, flag);
    }
    gemm_kernel<1><<<dim3(H_DIM / 128, T_TOKENS / 256, NE), 512, 0, stream>>>(
        act, wt2, b2, flag, token_list, wgt_list, counts, offsets, nullptr, yb,
        nullptr, nullptr, ctr, 0);
    combine_kernel<<<T_TOKENS, 256, 0, stream>>>(yb, assign_row, d_out, flag);
}

// Round 4
// 583.196 us; speedup vs baseline: 1.2610x; 1.2610x over previous
//
#include <hip/hip_runtime.h>
#include <hip/hip_bf16.h>
#include <stdint.h>

#define T_TOKENS 4096   // B*S
#define H_DIM    1024
#define F_DIM    4096
#define NE       8
#define NA       8192   // 2*T (total expert assignments)

typedef __bf16 bf16x8 __attribute__((ext_vector_type(8)));
typedef float  f32x4  __attribute__((ext_vector_type(4)));

__device__ __forceinline__ float b2f(unsigned short u) {
    union { float f; uint32_t i; } v; v.i = ((uint32_t)u) << 16; return v.f;
}
__device__ __forceinline__ unsigned short f2b(float f) {
    union { float f; uint32_t i; } v; v.f = f;
    uint32_t x = v.i;
    return (unsigned short)((x + 0x7FFFu + ((x >> 16) & 1u)) >> 16);
}

// exact GELU via A&S 7.1.26 erf (max err 1.5e-7), branchless, ~14 VALU + v_exp
__device__ __forceinline__ float gelu_f(float x) {
    float z = fabsf(x) * 0.70710678118f;
    float t = 1.0f / (1.0f + 0.3275911f * z);
    float p = t * (0.254829592f + t * (-0.284496736f +
              t * (1.421413741f + t * (-1.453152027f + t * 1.061405429f))));
    float erf_z = 1.0f - p * __expf(-z * z);
    float sgn_erf = (x >= 0.f) ? erf_z : -erf_z;
    return x * (0.5f + 0.5f * sgn_erf);
}

// async global->LDS, 16B per lane; LDS dest = wave-uniform base + lane*16.
__device__ __forceinline__ void gl_lds16(const void* g, void* l) {
    __builtin_amdgcn_global_load_lds(
        (const __attribute__((address_space(1))) void*)g,
        (__attribute__((address_space(3))) void*)l,
        16, 0, 0);
}

// ---- dtype probe: flag=1 if inputs are fp32, 0 if bf16 --------------------
__global__ void probe_kernel(const unsigned short* __restrict__ hs,
                             int* __restrict__ flag) {
    int lane = threadIdx.x;  // 64 threads
    int cnt = 0;
    for (int j = 0; j < 16; j++) {
        unsigned short u = hs[(lane * 16 + j) * 2];  // even indices only
        int e = (u >> 7) & 0xFF;
        if (e >= 100 && e <= 135) cnt++;
    }
    for (int off = 32; off > 0; off >>= 1) cnt += __shfl_down(cnt, off);
    if (lane == 0) *flag = (cnt >= 512) ? 0 : 1;  // bf16: ~1024, fp32: ~140
}

// ---- router (one wave per token) + fused hs->bf16 conversion --------------
__global__ __launch_bounds__(256) void router_kernel(
    const void* __restrict__ hs, const void* __restrict__ rw,
    const void* __restrict__ rb, const int* __restrict__ flag,
    int* __restrict__ top_i, float* __restrict__ top_w,
    unsigned short* __restrict__ hsb) {
    bool f32 = (*flag != 0);
    int wave = threadIdx.x >> 6, lane = threadIdx.x & 63;
    int t = blockIdx.x * 4 + wave;
    unsigned short* hout = hsb + (size_t)t * H_DIM;
    float acc[NE];
#pragma unroll
    for (int e = 0; e < NE; e++) acc[e] = 0.f;
    if (f32) {
        const float* hrow = (const float*)hs + (size_t)t * H_DIM;
        const float* rwf = (const float*)rw;
        for (int j = 0; j < 16; j++) {
            int k = j * 64 + lane;
            float h = hrow[k];
            hout[k] = f2b(h);
            float4 a = *(const float4*)(rwf + (size_t)k * NE);
            float4 b = *(const float4*)(rwf + (size_t)k * NE + 4);
            acc[0] += h * a.x; acc[1] += h * a.y; acc[2] += h * a.z; acc[3] += h * a.w;
            acc[4] += h * b.x; acc[5] += h * b.y; acc[6] += h * b.z; acc[7] += h * b.w;
        }
    } else {
        const unsigned short* hrow = (const unsigned short*)hs + (size_t)t * H_DIM;
        const unsigned short* rwu = (const unsigned short*)rw;
        for (int j = 0; j < 16; j++) {
            int k = j * 64 + lane;
            unsigned short hu = hrow[k];
            hout[k] = hu;
            float h = b2f(hu);
            uint4 rv = *(const uint4*)(rwu + (size_t)k * NE);
            const unsigned short* rs = (const unsigned short*)&rv;
#pragma unroll
            for (int e = 0; e < NE; e++) acc[e] += h * b2f(rs[e]);
        }
    }
#pragma unroll
    for (int e = 0; e < NE; e++)
        for (int off = 32; off > 0; off >>= 1) acc[e] += __shfl_down(acc[e], off);
    if (lane == 0) {
        float lg[NE];
#pragma unroll
        for (int e = 0; e < NE; e++)
            lg[e] = acc[e] + (f32 ? ((const float*)rb)[e]
                                  : b2f(((const unsigned short*)rb)[e]));
        int e0 = 0;
        for (int e = 1; e < NE; e++) if (lg[e] > lg[e0]) e0 = e;
        int e1 = (e0 == 0) ? 1 : 0;
        for (int e = 0; e < NE; e++) if (e != e0 && lg[e] > lg[e1]) e1 = e;
        float w0 = 1.f / (1.f + expf(lg[e1] - lg[e0]));
        top_i[t * 2] = e0; top_i[t * 2 + 1] = e1;
        top_w[t * 2] = w0; top_w[t * 2 + 1] = 1.f - w0;
    }
}

// ---- assignment build: one block ------------------------------------------
__global__ __launch_bounds__(256) void assign_kernel(
    const int* __restrict__ top_i, const float* __restrict__ top_w,
    int* __restrict__ token_list, float* __restrict__ wgt_list,
    int* __restrict__ assign_row, int* __restrict__ counts,
    int* __restrict__ offsets) {
    __shared__ int cnt_s[NE], cur_s[NE];
    int tid = threadIdx.x;
    if (tid < NE) cnt_s[tid] = 0;
    __syncthreads();
    for (int idx = tid; idx < NA; idx += 256) atomicAdd(&cnt_s[top_i[idx]], 1);
    __syncthreads();
    if (tid == 0) {
        int run = 0;
        for (int e = 0; e < NE; e++) {
            offsets[e] = run; counts[e] = cnt_s[e]; cur_s[e] = run; run += cnt_s[e];
        }
    }
    __syncthreads();
    for (int idx = tid; idx < NA; idx += 256) {
        int e = top_i[idx];
        int pos = atomicAdd(&cur_s[e], 1);
        token_list[pos] = idx >> 1;
        wgt_list[pos] = top_w[idx];
        assign_row[idx] = pos;
    }
}

// ---- 64x64 transpose to bf16 (from fp32 or bf16), per expert slice z ------
__global__ __launch_bounds__(256) void transpose_kernel(
    const void* __restrict__ in, unsigned short* __restrict__ out,
    int R, int C, const int* __restrict__ flag) {
    bool f32 = (*flag != 0);
    size_t zo = (size_t)blockIdx.z * R * C;
    int c0 = blockIdx.x * 64, r0 = blockIdx.y * 64;
    __shared__ unsigned short t[64][65];
    int tx = threadIdx.x & 15, ty = threadIdx.x >> 4;  // 16 col-groups x 16 rows
    if (f32) {
        const float* inf = (const float*)in + zo;
#pragma unroll
        for (int i = 0; i < 4; i++) {
            int r = ty + i * 16;
            float4 v = *(const float4*)&inf[(size_t)(r0 + r) * C + c0 + tx * 4];
            t[r][tx * 4] = f2b(v.x); t[r][tx * 4 + 1] = f2b(v.y);
            t[r][tx * 4 + 2] = f2b(v.z); t[r][tx * 4 + 3] = f2b(v.w);
        }
    } else {
        const unsigned short* inu = (const unsigned short*)in + zo;
#pragma unroll
        for (int i = 0; i < 4; i++) {
            int r = ty + i * 16;
            ushort4 v = *(const ushort4*)&inu[(size_t)(r0 + r) * C + c0 + tx * 4];
            t[r][tx * 4] = v.x; t[r][tx * 4 + 1] = v.y;
            t[r][tx * 4 + 2] = v.z; t[r][tx * 4 + 3] = v.w;
        }
    }
    __syncthreads();
#pragma unroll
    for (int i = 0; i < 4; i++) {
        int cc = ty + i * 16;
        ushort4 w;
        w.x = t[tx * 4][cc]; w.y = t[tx * 4 + 1][cc];
        w.z = t[tx * 4 + 2][cc]; w.w = t[tx * 4 + 3][cc];
        *(ushort4*)&out[zo + (size_t)(c0 + cc) * R + r0 + tx * 4] = w;
    }
}

// ---- grouped GEMM, 128x128 tile, 4 waves, BK=32 ---------------------------
// Pipeline (T3/T4-minimum): 3 LDS buffers, depth-1 prefetch, ONE raw barrier
// per K-step, counted s_waitcnt vmcnt(4) (never 0 in the loop).
//   iter kt: issue stage(kt+1 -> buf[(kt+1)%3]); vmcnt(4) [tile kt landed,
//   tile kt+1 stays in flight]; s_barrier; ds_read+MFMA from buf[kt%3].
// Safety: wave skew < 2 iters (1 barrier); readers use buf kt%3, writers
// touch (kt+1)%3 / (kt+2)%3 -> disjoint mod 3. Each wave writes only its own
// LDS slice, so per-wave FIFO vmcnt(4) + barrier covers cross-wave RAW.
// LDS row = 32 k-elems (64B = 4 chunks of 16B); row r chunk q at slot q^(r&3).
// MODE 0: act = gelu(hsb[gathered] @ w1t^T + b1)  -> bf16
// MODE 1: y   = (act @ w2t^T + b2) * slot_wgt     -> bf16
template <int MODE>
__global__ __launch_bounds__(256, 3) void gemm_kernel(
    const unsigned short* __restrict__ Abase,
    const unsigned short* __restrict__ Bt,   // [E][N][K] bf16 transposed weights
    const void* __restrict__ bias,           // [E][N] fp32 or bf16 per flag
    const int* __restrict__ flag,
    const int* __restrict__ token_list, const float* __restrict__ wgt_list,
    const int* __restrict__ counts, const int* __restrict__ offsets,
    unsigned short* __restrict__ act_out, unsigned short* __restrict__ y_out) {
    constexpr int K    = (MODE == 0) ? H_DIM : F_DIM;
    constexpr int NDIM = (MODE == 0) ? F_DIM : H_DIM;
    constexpr int AST  = K;
    constexpr int BM   = 128, BN = 128;
    constexpr int MI   = 4, NJ = 4;       // frags per wave (waves 2x2, 64x64 each)
    constexpr int NK   = K / 32;
    constexpr int ABUF = BM * 32;         // elements per A buffer (8 KB)
    constexpr int BBUF = BN * 32;
    constexpr int NIA  = 2, NIB = 2;      // staging instrs per wave

    // ---- bijective XCD-aware remap: e = lid % 8, n fastest within expert --
    const int lid = blockIdx.x + gridDim.x * (blockIdx.y + gridDim.y * blockIdx.z);
    const int e   = lid & 7;
    const int r_  = lid >> 3;
    const int nx  = r_ % gridDim.x;
    const int my  = r_ / gridDim.x;

    const int cnt = counts[e];
    const int m0 = my * BM;
    if (m0 >= cnt) return;
    const int off = offsets[e];
    const int n0 = nx * BN;
    const bool f32 = (*flag != 0);

    __shared__ __bf16 As[3 * ABUF];
    __shared__ __bf16 Bs[3 * BBUF];
    __shared__ int   tok_s[BM];
    __shared__ float wgt_s[BM];

    const int tid = threadIdx.x;
    const int wave = tid >> 6, lane = tid & 63;

    if (tid < BM) {
        int r = off + min(m0 + tid, cnt - 1);
        tok_s[tid] = (MODE == 0) ? token_list[r] : r;
        wgt_s[tid] = wgt_list[r];
    }
    __syncthreads();   // full drain: vmcnt baseline = 0 entering the pipeline

    // staging addresses (1KB per instr = 16 rows x 64B)
    const char* Abytes = (const char*)Abase;
    const char* Bbytes = (const char*)(Bt + (size_t)e * NDIM * K);
    const int rl = lane >> 2;                       // row within instr (0..15)
    const int chk = (lane & 3) ^ (rl & 3);          // global chunk fetched
    uint64_t ga[NIA], gb[NIB];
    uint32_t la[NIA], lb[NIB];
#pragma unroll
    for (int j = 0; j < NIA; j++) {
        int rowA = (wave * NIA + j) * 16 + rl;
        ga[j] = (uint64_t)(uintptr_t)(Abytes + ((size_t)tok_s[rowA] * AST + chk * 8) * 2);
        la[j] = (wave * NIA + j) * 512;             // element offset
    }
#pragma unroll
    for (int j = 0; j < NIB; j++) {
        int rowB = n0 + (wave * NIB + j) * 16 + rl;
        gb[j] = (uint64_t)(uintptr_t)(Bbytes + ((size_t)rowB * K + chk * 8) * 2);
        lb[j] = (wave * NIB + j) * 512;
    }

    f32x4 acc[MI][NJ];
#pragma unroll
    for (int i = 0; i < MI; i++)
#pragma unroll
        for (int j = 0; j < NJ; j++) acc[i][j] = (f32x4){0.f, 0.f, 0.f, 0.f};

    const int wr = wave >> 1, wc = wave & 1;
    const int lane15 = lane & 15, quad = lane >> 4;

    auto stage = [&](int buf) {
#pragma unroll
        for (int j = 0; j < NIA; j++) {
            gl_lds16((const void*)(uintptr_t)ga[j], (void*)(As + buf * ABUF + la[j]));
            ga[j] += 64;
        }
#pragma unroll
        for (int j = 0; j < NIB; j++) {
            gl_lds16((const void*)(uintptr_t)gb[j], (void*)(Bs + buf * BBUF + lb[j]));
            gb[j] += 64;
        }
    };
    auto compute = [&](int buf) {
        const __bf16* Ab = As + buf * ABUF;
        const __bf16* Bb = Bs + buf * BBUF;
        bf16x8 a[MI], b[NJ];
#pragma unroll
        for (int i = 0; i < MI; i++) {
            int row = wr * 64 + i * 16 + lane15;
            a[i] = *(const bf16x8*)&Ab[row * 32 + ((quad ^ (row & 3)) * 8)];
        }
#pragma unroll
        for (int j = 0; j < NJ; j++) {
            int row = wc * 64 + j * 16 + lane15;
            b[j] = *(const bf16x8*)&Bb[row * 32 + ((quad ^ (row & 3)) * 8)];
        }
        __builtin_amdgcn_s_setprio(1);
#pragma unroll
        for (int i = 0; i < MI; i++)
#pragma unroll
            for (int j = 0; j < NJ; j++)
                acc[i][j] = __builtin_amdgcn_mfma_f32_16x16x32_bf16(a[i], b[j], acc[i][j], 0, 0, 0);
        __builtin_amdgcn_s_setprio(0);
    };

    // prologue: tile 0 in flight
    stage(0);
    int bufw = 1, bufr = 0;
    for (int kt = 0; kt < NK - 1; kt++) {
        stage(bufw);                      // tile kt+1 -> in flight (8 loads out)
        bufw = (bufw == 2) ? 0 : bufw + 1;
        asm volatile("s_waitcnt vmcnt(4)" ::: "memory");  // tile kt landed
        __builtin_amdgcn_s_barrier();     // all waves' tile-kt loads landed
        __builtin_amdgcn_sched_barrier(0);
        compute(bufr);
        bufr = (bufr == 2) ? 0 : bufr + 1;
    }
    asm volatile("s_waitcnt vmcnt(0)" ::: "memory");      // drain last tile
    __builtin_amdgcn_s_barrier();
    __builtin_amdgcn_sched_barrier(0);
    compute(bufr);

    // epilogue: C/D layout col=lane&15, row=quad*4+reg
#pragma unroll
    for (int j = 0; j < NJ; j++) {
        int col = n0 + wc * 64 + j * 16 + lane15;
        float bv = f32 ? ((const float*)bias)[(size_t)e * NDIM + col]
                       : b2f(((const unsigned short*)bias)[(size_t)e * NDIM + col]);
#pragma unroll
        for (int i = 0; i < MI; i++) {
#pragma unroll
            for (int r = 0; r < 4; r++) {
                int rowl = wr * 64 + i * 16 + quad * 4 + r;
                if (m0 + rowl < cnt) {
                    float v = acc[i][j][r] + bv;
                    if (MODE == 0) {
                        act_out[(size_t)(off + m0 + rowl) * F_DIM + col] = f2b(gelu_f(v));
                    } else {
                        y_out[(size_t)(off + m0 + rowl) * H_DIM + col] = f2b(v * wgt_s[rowl]);
                    }
                }
            }
        }
    }
}

// ---- combine: out[t] = y[slot0] + y[slot1]; write bf16 or fp32 ------------
__global__ __launch_bounds__(256) void combine_kernel(
    const unsigned short* __restrict__ y, const int* __restrict__ assign_row,
    void* __restrict__ out, const int* __restrict__ flag) {
    bool f32 = (*flag != 0);
    int t = blockIdx.x;
    int r0 = assign_row[t * 2], r1 = assign_row[t * 2 + 1];
    ushort4 a = ((const ushort4*)(y + (size_t)r0 * H_DIM))[threadIdx.x];
    ushort4 b = ((const ushort4*)(y + (size_t)r1 * H_DIM))[threadIdx.x];
    float s0 = b2f(a.x) + b2f(b.x), s1 = b2f(a.y) + b2f(b.y);
    float s2 = b2f(a.z) + b2f(b.z), s3 = b2f(a.w) + b2f(b.w);
    if (f32) {
        float4 o = {s0, s1, s2, s3};
        ((float4*)out)[(size_t)t * (H_DIM / 4) + threadIdx.x] = o;
    } else {
        ushort4 o;
        o.x = f2b(s0); o.y = f2b(s1); o.z = f2b(s2); o.w = f2b(s3);
        ((ushort4*)((unsigned short*)out + (size_t)t * H_DIM))[threadIdx.x] = o;
    }
}

extern "C" void kernel_launch(void* const* d_in, const int* in_sizes, int n_in,
                              void* d_out, int out_size, void* d_ws, size_t ws_size,
                              hipStream_t stream) {
    const void* hs = d_in[0];
    const void* rw = d_in[1];
    const void* rb = d_in[2];
    const void* w1 = d_in[3];
    const void* b1 = d_in[4];
    const void* w2 = d_in[5];
    const void* b2 = d_in[6];

    char* ws = (char*)d_ws;
    size_t o = 0;
    auto alloc = [&](size_t bytes) {
        char* p = ws + o; o += (bytes + 255) & ~(size_t)255; return p;
    };
    unsigned short* wt   = (unsigned short*)alloc((size_t)NE * F_DIM * H_DIM * 2);  // 64 MB (reused)
    unsigned short* act  = (unsigned short*)alloc((size_t)NA * F_DIM * 2);          // 64 MB
    unsigned short* yb   = (unsigned short*)alloc((size_t)NA * H_DIM * 2);          // 16 MB
    unsigned short* hsb  = (unsigned short*)alloc((size_t)T_TOKENS * H_DIM * 2);    //  8 MB
    int*   top_i      = (int*)alloc(NA * 4);
    float* top_w      = (float*)alloc(NA * 4);
    int*   token_list = (int*)alloc(NA * 4);
    float* wgt_list   = (float*)alloc(NA * 4);
    int*   assign_row = (int*)alloc(NA * 4);
    int*   counts     = (int*)alloc(64);
    int*   offsets    = (int*)alloc(64);
    int*   flag       = (int*)alloc(64);
    (void)ws_size; (void)in_sizes; (void)n_in; (void)out_size;

    probe_kernel<<<1, 64, 0, stream>>>((const unsigned short*)hs, flag);
    router_kernel<<<T_TOKENS / 4, 256, 0, stream>>>(hs, rw, rb, flag, top_i, top_w, hsb);
    assign_kernel<<<1, 256, 0, stream>>>(top_i, top_w, token_list, wgt_list,
                                         assign_row, counts, offsets);
    transpose_kernel<<<dim3(F_DIM / 64, H_DIM / 64, NE), 256, 0, stream>>>(
        w1, wt, H_DIM, F_DIM, flag);
    gemm_kernel<0><<<dim3(F_DIM / 128, T_TOKENS / 128, NE), 256, 0, stream>>>(
        hsb, wt, b1, flag, token_list, wgt_list, counts, offsets, act, nullptr);
    transpose_kernel<<<dim3(H_DIM / 64, F_DIM / 64, NE), 256, 0, stream>>>(
        w2, wt, F_DIM, H_DIM, flag);
    gemm_kernel<1><<<dim3(H_DIM / 128, T_TOKENS / 128, NE), 256, 0, stream>>>(
        act, wt, b2, flag, token_list, wgt_list, counts, offsets, nullptr, yb);
    combine_kernel<<<T_TOKENS, 256, 0, stream>>>(yb, assign_row, d_out, flag);
}

// Round 5
// 567.324 us; speedup vs baseline: 1.2963x; 1.0280x over previous
//
#include <hip/hip_runtime.h>
#include <hip/hip_bf16.h>
#include <stdint.h>

#define T_TOKENS 4096   // B*S
#define H_DIM    1024
#define F_DIM    4096
#define NE       8
#define NA       8192   // 2*T (total expert assignments)

typedef __bf16 bf16x8 __attribute__((ext_vector_type(8)));
typedef float  f32x4  __attribute__((ext_vector_type(4)));
typedef unsigned short u16x4v __attribute__((ext_vector_type(4)));

__device__ __forceinline__ float b2f(unsigned short u) {
    union { float f; uint32_t i; } v; v.i = ((uint32_t)u) << 16; return v.f;
}
__device__ __forceinline__ unsigned short f2b(float f) {
    union { float f; uint32_t i; } v; v.f = f;
    uint32_t x = v.i;
    return (unsigned short)((x + 0x7FFFu + ((x >> 16) & 1u)) >> 16);
}

// exact GELU via A&S 7.1.26 erf (max err 1.5e-7), branchless, ~14 VALU + v_exp
__device__ __forceinline__ float gelu_f(float x) {
    float z = fabsf(x) * 0.70710678118f;
    float t = 1.0f / (1.0f + 0.3275911f * z);
    float p = t * (0.254829592f + t * (-0.284496736f +
              t * (1.421413741f + t * (-1.453152027f + t * 1.061405429f))));
    float erf_z = 1.0f - p * __expf(-z * z);
    float sgn_erf = (x >= 0.f) ? erf_z : -erf_z;
    return x * (0.5f + 0.5f * sgn_erf);
}

// async global->LDS, 16B per lane; LDS dest = wave-uniform base + lane*16.
__device__ __forceinline__ void gl_lds16(const void* g, void* l) {
    __builtin_amdgcn_global_load_lds(
        (const __attribute__((address_space(1))) void*)g,
        (__attribute__((address_space(3))) void*)l,
        16, 0, 0);
}

// ---- dtype probe: flag=1 if inputs are fp32, 0 if bf16 --------------------
__global__ void probe_kernel(const unsigned short* __restrict__ hs,
                             int* __restrict__ flag) {
    int lane = threadIdx.x;  // 64 threads
    int cnt = 0;
    for (int j = 0; j < 16; j++) {
        unsigned short u = hs[(lane * 16 + j) * 2];  // even indices only
        int e = (u >> 7) & 0xFF;
        if (e >= 100 && e <= 135) cnt++;
    }
    for (int off = 32; off > 0; off >>= 1) cnt += __shfl_down(cnt, off);
    if (lane == 0) *flag = (cnt >= 512) ? 0 : 1;  // bf16: ~1024, fp32: ~140
}

// ---- router (one wave per token) + fused hs->bf16 conversion --------------
__global__ __launch_bounds__(256) void router_kernel(
    const void* __restrict__ hs, const void* __restrict__ rw,
    const void* __restrict__ rb, const int* __restrict__ flag,
    int* __restrict__ top_i, float* __restrict__ top_w,
    unsigned short* __restrict__ hsb) {
    bool f32 = (*flag != 0);
    int wave = threadIdx.x >> 6, lane = threadIdx.x & 63;
    int t = blockIdx.x * 4 + wave;
    unsigned short* hout = hsb + (size_t)t * H_DIM;
    float acc[NE];
#pragma unroll
    for (int e = 0; e < NE; e++) acc[e] = 0.f;
    if (f32) {
        const float* hrow = (const float*)hs + (size_t)t * H_DIM;
        const float* rwf = (const float*)rw;
        for (int j = 0; j < 16; j++) {
            int k = j * 64 + lane;
            float h = hrow[k];
            hout[k] = f2b(h);
            float4 a = *(const float4*)(rwf + (size_t)k * NE);
            float4 b = *(const float4*)(rwf + (size_t)k * NE + 4);
            acc[0] += h * a.x; acc[1] += h * a.y; acc[2] += h * a.z; acc[3] += h * a.w;
            acc[4] += h * b.x; acc[5] += h * b.y; acc[6] += h * b.z; acc[7] += h * b.w;
        }
    } else {
        const unsigned short* hrow = (const unsigned short*)hs + (size_t)t * H_DIM;
        const unsigned short* rwu = (const unsigned short*)rw;
        for (int j = 0; j < 16; j++) {
            int k = j * 64 + lane;
            unsigned short hu = hrow[k];
            hout[k] = hu;
            float h = b2f(hu);
            uint4 rv = *(const uint4*)(rwu + (size_t)k * NE);
            const unsigned short* rs = (const unsigned short*)&rv;
#pragma unroll
            for (int e = 0; e < NE; e++) acc[e] += h * b2f(rs[e]);
        }
    }
#pragma unroll
    for (int e = 0; e < NE; e++)
        for (int off = 32; off > 0; off >>= 1) acc[e] += __shfl_down(acc[e], off);
    if (lane == 0) {
        float lg[NE];
#pragma unroll
        for (int e = 0; e < NE; e++)
            lg[e] = acc[e] + (f32 ? ((const float*)rb)[e]
                                  : b2f(((const unsigned short*)rb)[e]));
        int e0 = 0;
        for (int e = 1; e < NE; e++) if (lg[e] > lg[e0]) e0 = e;
        int e1 = (e0 == 0) ? 1 : 0;
        for (int e = 0; e < NE; e++) if (e != e0 && lg[e] > lg[e1]) e1 = e;
        float w0 = 1.f / (1.f + expf(lg[e1] - lg[e0]));
        top_i[t * 2] = e0; top_i[t * 2 + 1] = e1;
        top_w[t * 2] = w0; top_w[t * 2 + 1] = 1.f - w0;
    }
}

// ---- assignment build: one block ------------------------------------------
__global__ __launch_bounds__(256) void assign_kernel(
    const int* __restrict__ top_i, const float* __restrict__ top_w,
    int* __restrict__ token_list, float* __restrict__ wgt_list,
    int* __restrict__ assign_row, int* __restrict__ counts,
    int* __restrict__ offsets) {
    __shared__ int cnt_s[NE], cur_s[NE];
    int tid = threadIdx.x;
    if (tid < NE) cnt_s[tid] = 0;
    __syncthreads();
    for (int idx = tid; idx < NA; idx += 256) atomicAdd(&cnt_s[top_i[idx]], 1);
    __syncthreads();
    if (tid == 0) {
        int run = 0;
        for (int e = 0; e < NE; e++) {
            offsets[e] = run; counts[e] = cnt_s[e]; cur_s[e] = run; run += cnt_s[e];
        }
    }
    __syncthreads();
    for (int idx = tid; idx < NA; idx += 256) {
        int e = top_i[idx];
        int pos = atomicAdd(&cur_s[e], 1);
        token_list[pos] = idx >> 1;
        wgt_list[pos] = top_w[idx];
        assign_row[idx] = pos;
    }
}

// ---- 64x64 transpose to bf16 (from fp32 or bf16), per expert slice z ------
__global__ __launch_bounds__(256) void transpose_kernel(
    const void* __restrict__ in, unsigned short* __restrict__ out,
    int R, int C, const int* __restrict__ flag) {
    bool f32 = (*flag != 0);
    size_t zo = (size_t)blockIdx.z * R * C;
    int c0 = blockIdx.x * 64, r0 = blockIdx.y * 64;
    __shared__ unsigned short t[64][65];
    int tx = threadIdx.x & 15, ty = threadIdx.x >> 4;  // 16 col-groups x 16 rows
    if (f32) {
        const float* inf = (const float*)in + zo;
#pragma unroll
        for (int i = 0; i < 4; i++) {
            int r = ty + i * 16;
            float4 v = *(const float4*)&inf[(size_t)(r0 + r) * C + c0 + tx * 4];
            t[r][tx * 4] = f2b(v.x); t[r][tx * 4 + 1] = f2b(v.y);
            t[r][tx * 4 + 2] = f2b(v.z); t[r][tx * 4 + 3] = f2b(v.w);
        }
    } else {
        const unsigned short* inu = (const unsigned short*)in + zo;
#pragma unroll
        for (int i = 0; i < 4; i++) {
            int r = ty + i * 16;
            ushort4 v = *(const ushort4*)&inu[(size_t)(r0 + r) * C + c0 + tx * 4];
            t[r][tx * 4] = v.x; t[r][tx * 4 + 1] = v.y;
            t[r][tx * 4 + 2] = v.z; t[r][tx * 4 + 3] = v.w;
        }
    }
    __syncthreads();
#pragma unroll
    for (int i = 0; i < 4; i++) {
        int cc = ty + i * 16;
        ushort4 w;
        w.x = t[tx * 4][cc]; w.y = t[tx * 4 + 1][cc];
        w.z = t[tx * 4 + 2][cc]; w.w = t[tx * 4 + 3][cc];
        *(ushort4*)&out[zo + (size_t)(c0 + cc) * R + r0 + tx * 4] = w;
    }
}

// ---- grouped GEMM, 128x128 tile, 4 waves, BK=32 ---------------------------
// Pipeline (T3/T4-minimum, verified R4): 3 LDS buffers, depth-1 prefetch, ONE
// raw barrier per K-step, counted s_waitcnt vmcnt(4) (never 0 in the loop).
// SWAPPED MFMA OPERANDS: acc = mfma(b, a, acc) computes C^T in fragment space
//   -> lane holds row = lane&15, cols = quad*4 + reg (4 CONSECUTIVE cols)
//   -> epilogue stores are 8B-contiguous u16x4 (was 64 scattered 2B stores).
// LDS row = 32 k-elems (64B = 4 chunks of 16B); row r chunk q at slot q^(r&3).
// MODE 0: act = gelu(hsb[gathered] @ w1t^T + b1)  -> bf16
// MODE 1: y   = (act @ w2t^T + b2) * slot_wgt     -> bf16
template <int MODE>
__global__ __launch_bounds__(256, 3) void gemm_kernel(
    const unsigned short* __restrict__ Abase,
    const unsigned short* __restrict__ Bt,   // [E][N][K] bf16 transposed weights
    const void* __restrict__ bias,           // [E][N] fp32 or bf16 per flag
    const int* __restrict__ flag,
    const int* __restrict__ token_list, const float* __restrict__ wgt_list,
    const int* __restrict__ counts, const int* __restrict__ offsets,
    unsigned short* __restrict__ act_out, unsigned short* __restrict__ y_out) {
    constexpr int K    = (MODE == 0) ? H_DIM : F_DIM;
    constexpr int NDIM = (MODE == 0) ? F_DIM : H_DIM;
    constexpr int AST  = K;
    constexpr int BM   = 128, BN = 128;
    constexpr int MI   = 4, NJ = 4;       // frags per wave (waves 2x2, 64x64 each)
    constexpr int NK   = K / 32;
    constexpr int ABUF = BM * 32;         // elements per A buffer (8 KB)
    constexpr int BBUF = BN * 32;
    constexpr int NIA  = 2, NIB = 2;      // staging instrs per wave

    // ---- bijective XCD-aware remap: e = lid % 8, n fastest within expert --
    const int lid = blockIdx.x + gridDim.x * (blockIdx.y + gridDim.y * blockIdx.z);
    const int e   = lid & 7;
    const int r_  = lid >> 3;
    const int nx  = r_ % gridDim.x;
    const int my  = r_ / gridDim.x;

    const int cnt = counts[e];
    const int m0 = my * BM;
    if (m0 >= cnt) return;
    const int off = offsets[e];
    const int n0 = nx * BN;
    const bool f32 = (*flag != 0);

    __shared__ __bf16 As[3 * ABUF];
    __shared__ __bf16 Bs[3 * BBUF];
    __shared__ int   tok_s[BM];
    __shared__ float wgt_s[BM];

    const int tid = threadIdx.x;
    const int wave = tid >> 6, lane = tid & 63;

    if (tid < BM) {
        int r = off + min(m0 + tid, cnt - 1);
        tok_s[tid] = (MODE == 0) ? token_list[r] : r;
        wgt_s[tid] = wgt_list[r];
    }
    __syncthreads();   // full drain: vmcnt baseline = 0 entering the pipeline

    // staging addresses (1KB per instr = 16 rows x 64B)
    const char* Abytes = (const char*)Abase;
    const char* Bbytes = (const char*)(Bt + (size_t)e * NDIM * K);
    const int rl = lane >> 2;                       // row within instr (0..15)
    const int chk = (lane & 3) ^ (rl & 3);          // global chunk fetched
    uint64_t ga[NIA], gb[NIB];
    uint32_t la[NIA], lb[NIB];
#pragma unroll
    for (int j = 0; j < NIA; j++) {
        int rowA = (wave * NIA + j) * 16 + rl;
        ga[j] = (uint64_t)(uintptr_t)(Abytes + ((size_t)tok_s[rowA] * AST + chk * 8) * 2);
        la[j] = (wave * NIA + j) * 512;             // element offset
    }
#pragma unroll
    for (int j = 0; j < NIB; j++) {
        int rowB = n0 + (wave * NIB + j) * 16 + rl;
        gb[j] = (uint64_t)(uintptr_t)(Bbytes + ((size_t)rowB * K + chk * 8) * 2);
        lb[j] = (wave * NIB + j) * 512;
    }

    f32x4 acc[MI][NJ];
#pragma unroll
    for (int i = 0; i < MI; i++)
#pragma unroll
        for (int j = 0; j < NJ; j++) acc[i][j] = (f32x4){0.f, 0.f, 0.f, 0.f};

    const int wr = wave >> 1, wc = wave & 1;
    const int lane15 = lane & 15, quad = lane >> 4;

    auto stage = [&](int buf) {
#pragma unroll
        for (int j = 0; j < NIA; j++) {
            gl_lds16((const void*)(uintptr_t)ga[j], (void*)(As + buf * ABUF + la[j]));
            ga[j] += 64;
        }
#pragma unroll
        for (int j = 0; j < NIB; j++) {
            gl_lds16((const void*)(uintptr_t)gb[j], (void*)(Bs + buf * BBUF + lb[j]));
            gb[j] += 64;
        }
    };
    auto compute = [&](int buf) {
        const __bf16* Ab = As + buf * ABUF;
        const __bf16* Bb = Bs + buf * BBUF;
        bf16x8 a[MI], b[NJ];
#pragma unroll
        for (int i = 0; i < MI; i++) {
            int row = wr * 64 + i * 16 + lane15;
            a[i] = *(const bf16x8*)&Ab[row * 32 + ((quad ^ (row & 3)) * 8)];
        }
#pragma unroll
        for (int j = 0; j < NJ; j++) {
            int row = wc * 64 + j * 16 + lane15;
            b[j] = *(const bf16x8*)&Bb[row * 32 + ((quad ^ (row & 3)) * 8)];
        }
        __builtin_amdgcn_s_setprio(1);
#pragma unroll
        for (int i = 0; i < MI; i++)
#pragma unroll
            for (int j = 0; j < NJ; j++)
                acc[i][j] = __builtin_amdgcn_mfma_f32_16x16x32_bf16(b[j], a[i], acc[i][j], 0, 0, 0);
        __builtin_amdgcn_s_setprio(0);
    };

    // prologue: tile 0 in flight
    stage(0);
    int bufw = 1, bufr = 0;
    for (int kt = 0; kt < NK - 1; kt++) {
        stage(bufw);                      // tile kt+1 -> in flight (8 loads out)
        bufw = (bufw == 2) ? 0 : bufw + 1;
        asm volatile("s_waitcnt vmcnt(4)" ::: "memory");  // tile kt landed
        __builtin_amdgcn_s_barrier();     // all waves' tile-kt loads landed
        __builtin_amdgcn_sched_barrier(0);
        compute(bufr);
        bufr = (bufr == 2) ? 0 : bufr + 1;
    }
    asm volatile("s_waitcnt vmcnt(0)" ::: "memory");      // drain last tile
    __builtin_amdgcn_s_barrier();
    __builtin_amdgcn_sched_barrier(0);
    compute(bufr);

    // epilogue (swapped-operand layout): row = lane&15 (+16i), col = quad*4+r
    unsigned short* outp = (MODE == 0) ? act_out : y_out;
#pragma unroll
    for (int i = 0; i < MI; i++) {
        int rowl = wr * 64 + i * 16 + lane15;
        if (m0 + rowl < cnt) {
            size_t gbase = (size_t)(off + m0 + rowl) * NDIM;
            float wgt = wgt_s[rowl];
#pragma unroll
            for (int j = 0; j < NJ; j++) {
                int col = n0 + wc * 64 + j * 16 + quad * 4;
                float bb[4];
                if (f32) {
                    float4 bf4 = *(const float4*)((const float*)bias + (size_t)e * NDIM + col);
                    bb[0] = bf4.x; bb[1] = bf4.y; bb[2] = bf4.z; bb[3] = bf4.w;
                } else {
                    ushort4 bu = *(const ushort4*)((const unsigned short*)bias + (size_t)e * NDIM + col);
                    bb[0] = b2f(bu.x); bb[1] = b2f(bu.y); bb[2] = b2f(bu.z); bb[3] = b2f(bu.w);
                }
                u16x4v o;
#pragma unroll
                for (int r = 0; r < 4; r++) {
                    float v = acc[i][j][r] + bb[r];
                    o[r] = (MODE == 0) ? f2b(gelu_f(v)) : f2b(v * wgt);
                }
                *(u16x4v*)&outp[gbase + col] = o;
            }
        }
    }
}

// ---- combine: out[t] = y[slot0] + y[slot1]; write bf16 or fp32 ------------
__global__ __launch_bounds__(256) void combine_kernel(
    const unsigned short* __restrict__ y, const int* __restrict__ assign_row,
    void* __restrict__ out, const int* __restrict__ flag) {
    bool f32 = (*flag != 0);
    int t = blockIdx.x;
    int r0 = assign_row[t * 2], r1 = assign_row[t * 2 + 1];
    ushort4 a = ((const ushort4*)(y + (size_t)r0 * H_DIM))[threadIdx.x];
    ushort4 b = ((const ushort4*)(y + (size_t)r1 * H_DIM))[threadIdx.x];
    float s0 = b2f(a.x) + b2f(b.x), s1 = b2f(a.y) + b2f(b.y);
    float s2 = b2f(a.z) + b2f(b.z), s3 = b2f(a.w) + b2f(b.w);
    if (f32) {
        float4 o = {s0, s1, s2, s3};
        ((float4*)out)[(size_t)t * (H_DIM / 4) + threadIdx.x] = o;
    } else {
        ushort4 o;
        o.x = f2b(s0); o.y = f2b(s1); o.z = f2b(s2); o.w = f2b(s3);
        ((ushort4*)((unsigned short*)out + (size_t)t * H_DIM))[threadIdx.x] = o;
    }
}

extern "C" void kernel_launch(void* const* d_in, const int* in_sizes, int n_in,
                              void* d_out, int out_size, void* d_ws, size_t ws_size,
                              hipStream_t stream) {
    const void* hs = d_in[0];
    const void* rw = d_in[1];
    const void* rb = d_in[2];
    const void* w1 = d_in[3];
    const void* b1 = d_in[4];
    const void* w2 = d_in[5];
    const void* b2 = d_in[6];

    char* ws = (char*)d_ws;
    size_t o = 0;
    auto alloc = [&](size_t bytes) {
        char* p = ws + o; o += (bytes + 255) & ~(size_t)255; return p;
    };
    unsigned short* wt   = (unsigned short*)alloc((size_t)NE * F_DIM * H_DIM * 2);  // 64 MB (reused)
    unsigned short* act  = (unsigned short*)alloc((size_t)NA * F_DIM * 2);          // 64 MB
    unsigned short* yb   = (unsigned short*)alloc((size_t)NA * H_DIM * 2);          // 16 MB
    unsigned short* hsb  = (unsigned short*)alloc((size_t)T_TOKENS * H_DIM * 2);    //  8 MB
    int*   top_i      = (int*)alloc(NA * 4);
    float* top_w      = (float*)alloc(NA * 4);
    int*   token_list = (int*)alloc(NA * 4);
    float* wgt_list   = (float*)alloc(NA * 4);
    int*   assign_row = (int*)alloc(NA * 4);
    int*   counts     = (int*)alloc(64);
    int*   offsets    = (int*)alloc(64);
    int*   flag       = (int*)alloc(64);
    (void)ws_size; (void)in_sizes; (void)n_in; (void)out_size;

    probe_kernel<<<1, 64, 0, stream>>>((const unsigned short*)hs, flag);
    router_kernel<<<T_TOKENS / 4, 256, 0, stream>>>(hs, rw, rb, flag, top_i, top_w, hsb);
    assign_kernel<<<1, 256, 0, stream>>>(top_i, top_w, token_list, wgt_list,
                                         assign_row, counts, offsets);
    transpose_kernel<<<dim3(F_DIM / 64, H_DIM / 64, NE), 256, 0, stream>>>(
        w1, wt, H_DIM, F_DIM, flag);
    gemm_kernel<0><<<dim3(F_DIM / 128, T_TOKENS / 128, NE), 256, 0, stream>>>(
        hsb, wt, b1, flag, token_list, wgt_list, counts, offsets, act, nullptr);
    transpose_kernel<<<dim3(H_DIM / 64, F_DIM / 64, NE), 256, 0, stream>>>(
        w2, wt, F_DIM, H_DIM, flag);
    gemm_kernel<1><<<dim3(H_DIM / 128, T_TOKENS / 128, NE), 256, 0, stream>>>(
        act, wt, b2, flag, token_list, wgt_list, counts, offsets, nullptr, yb);
    combine_kernel<<<T_TOKENS, 256, 0, stream>>>(yb, assign_row, d_out, flag);
}